// Round 1
// baseline (689.261 us; speedup 1.0000x reference)
//
#include <hip/hip_runtime.h>

#define BB 4
#define SS 1024
#define DD 1024
#define HH 16
#define DHH 64
#define MT (BB*SS)   // 4096 rows for QKV projection

typedef __bf16 bf16x8 __attribute__((ext_vector_type(8)));
typedef unsigned short u16x8 __attribute__((ext_vector_type(8)));
typedef float f32x4 __attribute__((ext_vector_type(4)));

__device__ __forceinline__ bf16x8 as_bf16x8(u16x8 u) {
  union { u16x8 u; bf16x8 b; } c; c.u = u; return c.b;
}
// fp32 -> bf16 RNE via bit trick (avoids any __bf16 scalar-conversion surprises)
__device__ __forceinline__ unsigned short f2bf(float f) {
  unsigned int u = __float_as_uint(f);
  return (unsigned short)((u + 0x7fffu + ((u >> 16) & 1u)) >> 16);
}

#define MFMA(a, b, c) __builtin_amdgcn_mfma_f32_16x16x32_bf16((a), (b), (c), 0, 0, 0)

// ---------------------------------------------------------------------------
// Kernel 1: Out(bf16) = X(MxK fp32) @ W(KxN fp32) + bias.  M=4096,N=K=1024.
// 64x64 block tile, BK=32, 4 waves (2x2), each wave 32x32 via 2x2 MFMA tiles.
// ---------------------------------------------------------------------------
__global__ __launch_bounds__(256) void gemm_xw(
    const float* __restrict__ X, const float* __restrict__ W,
    const float* __restrict__ bias, unsigned short* __restrict__ Out)
{
  __shared__ unsigned short As[64][40];   // As[m][k], +8 pad keeps 16B align, breaks bank stride
  __shared__ unsigned short Bs[64][40];   // transposed: Bs[n][k]
  const int tid  = threadIdx.x;
  const int lane = tid & 63, wave = tid >> 6;
  const int quad = lane >> 4, l16 = lane & 15;
  const int wm = (wave >> 1) * 32, wn = (wave & 1) * 32;
  const int m0 = blockIdx.x * 64, n0 = blockIdx.y * 64;
  const int ar = tid >> 2, ac = (tid & 3) * 8;   // A staging: 64 rows x 32 cols
  const int bk = tid >> 3, bn = (tid & 7) * 8;   // B staging: 32 k x 64 n

  f32x4 acc[2][2] = {};

  for (int k0 = 0; k0 < DD; k0 += 32) {
    const float* xa = X + (size_t)(m0 + ar) * DD + k0 + ac;
    float4 a0 = *(const float4*)xa;
    float4 a1 = *(const float4*)(xa + 4);
    const float* wp = W + (size_t)(k0 + bk) * DD + n0 + bn;
    float4 b0 = *(const float4*)wp;
    float4 b1 = *(const float4*)(wp + 4);

    unsigned short* da = &As[ar][ac];
    da[0]=f2bf(a0.x); da[1]=f2bf(a0.y); da[2]=f2bf(a0.z); da[3]=f2bf(a0.w);
    da[4]=f2bf(a1.x); da[5]=f2bf(a1.y); da[6]=f2bf(a1.z); da[7]=f2bf(a1.w);
    Bs[bn+0][bk]=f2bf(b0.x); Bs[bn+1][bk]=f2bf(b0.y);
    Bs[bn+2][bk]=f2bf(b0.z); Bs[bn+3][bk]=f2bf(b0.w);
    Bs[bn+4][bk]=f2bf(b1.x); Bs[bn+5][bk]=f2bf(b1.y);
    Bs[bn+6][bk]=f2bf(b1.z); Bs[bn+7][bk]=f2bf(b1.w);
    __syncthreads();

    bf16x8 af0 = as_bf16x8(*(const u16x8*)&As[wm      + l16][quad*8]);
    bf16x8 af1 = as_bf16x8(*(const u16x8*)&As[wm + 16 + l16][quad*8]);
    bf16x8 bf0 = as_bf16x8(*(const u16x8*)&Bs[wn      + l16][quad*8]);
    bf16x8 bf1 = as_bf16x8(*(const u16x8*)&Bs[wn + 16 + l16][quad*8]);
    acc[0][0] = MFMA(af0, bf0, acc[0][0]);
    acc[0][1] = MFMA(af0, bf1, acc[0][1]);
    acc[1][0] = MFMA(af1, bf0, acc[1][0]);
    acc[1][1] = MFMA(af1, bf1, acc[1][1]);
    __syncthreads();
  }

  #pragma unroll
  for (int i = 0; i < 2; i++)
    #pragma unroll
    for (int j = 0; j < 2; j++) {
      const int col = n0 + wn + j*16 + l16;
      const float bsv = bias[col];
      #pragma unroll
      for (int r = 0; r < 4; r++) {
        const int row = m0 + wm + i*16 + quad*4 + r;
        Out[(size_t)row * DD + col] = f2bf(acc[i][j][r] + bsv);
      }
    }
}

// ---------------------------------------------------------------------------
// Kernel 2: scores[z=h*B+b][q][c] = (Q_h . K_h) / 8, written fp32 to d_out
// attn region. 64x64 tile per block, dh=64 K-loop (2 iters), frags straight
// from global bf16 (no LDS).
// ---------------------------------------------------------------------------
__global__ __launch_bounds__(256) void qk_scores(
    const unsigned short* __restrict__ Qb, const unsigned short* __restrict__ Kb,
    float* __restrict__ attn)
{
  const int tid  = threadIdx.x;
  const int lane = tid & 63, wave = tid >> 6;
  const int quad = lane >> 4, l16 = lane & 15;
  const int wm = (wave >> 1) * 32, wn = (wave & 1) * 32;
  const int q0 = blockIdx.x * 64, c0 = blockIdx.y * 64;
  const int z = blockIdx.z;            // z = h*B + b  (heads-major output)
  const int b = z & 3, h = z >> 2;

  f32x4 acc[2][2] = {};
  const unsigned short* qbase = Qb + (size_t)(b * SS) * DD + h * DHH;
  const unsigned short* kbase = Kb + (size_t)(b * SS) * DD + h * DHH;

  #pragma unroll
  for (int k0 = 0; k0 < DHH; k0 += 32) {
    bf16x8 a0 = as_bf16x8(*(const u16x8*)(qbase + (size_t)(q0+wm   +l16)*DD + k0 + quad*8));
    bf16x8 a1 = as_bf16x8(*(const u16x8*)(qbase + (size_t)(q0+wm+16+l16)*DD + k0 + quad*8));
    bf16x8 b0 = as_bf16x8(*(const u16x8*)(kbase + (size_t)(c0+wn   +l16)*DD + k0 + quad*8));
    bf16x8 b1 = as_bf16x8(*(const u16x8*)(kbase + (size_t)(c0+wn+16+l16)*DD + k0 + quad*8));
    acc[0][0] = MFMA(a0, b0, acc[0][0]);
    acc[0][1] = MFMA(a0, b1, acc[0][1]);
    acc[1][0] = MFMA(a1, b0, acc[1][0]);
    acc[1][1] = MFMA(a1, b1, acc[1][1]);
  }

  float* obase = attn + (size_t)z * SS * SS;
  #pragma unroll
  for (int i = 0; i < 2; i++)
    #pragma unroll
    for (int j = 0; j < 2; j++) {
      const int col = c0 + wn + j*16 + l16;
      #pragma unroll
      for (int r = 0; r < 4; r++) {
        const int row = q0 + wm + i*16 + quad*4 + r;
        obase[(size_t)row * SS + col] = acc[i][j][r] * 0.125f;
      }
    }
}

// ---------------------------------------------------------------------------
// Kernel 3: in-place row softmax over 65536 rows x 1024. One wave per row,
// 16 fp32/lane, shuffle reductions (no LDS, no __syncthreads).
// ---------------------------------------------------------------------------
__global__ __launch_bounds__(256) void softmax_rows(float* __restrict__ attn)
{
  const int wave = threadIdx.x >> 6, lane = threadIdx.x & 63;
  const size_t row = (size_t)blockIdx.x * 4 + wave;
  float* p = attn + row * SS;

  float4 v[4];
  float m = -3.4e38f;
  #pragma unroll
  for (int c = 0; c < 4; c++) {
    v[c] = *(const float4*)(p + c*256 + lane*4);
    m = fmaxf(m, fmaxf(fmaxf(v[c].x, v[c].y), fmaxf(v[c].z, v[c].w)));
  }
  #pragma unroll
  for (int off = 32; off > 0; off >>= 1) m = fmaxf(m, __shfl_xor(m, off));

  float s = 0.f;
  #pragma unroll
  for (int c = 0; c < 4; c++) {
    v[c].x = __expf(v[c].x - m); v[c].y = __expf(v[c].y - m);
    v[c].z = __expf(v[c].z - m); v[c].w = __expf(v[c].w - m);
    s += v[c].x + v[c].y + v[c].z + v[c].w;
  }
  #pragma unroll
  for (int off = 32; off > 0; off >>= 1) s += __shfl_xor(s, off);

  const float inv = 1.0f / s;
  #pragma unroll
  for (int c = 0; c < 4; c++) {
    v[c].x *= inv; v[c].y *= inv; v[c].z *= inv; v[c].w *= inv;
    *(float4*)(p + c*256 + lane*4) = v[c];
  }
}

// ---------------------------------------------------------------------------
// Kernel 4: context = attn @ V_h.  Per (q-tile, z): M=64 rows, N=dh=64,
// K=1024. A from global fp32 attn (converted to bf16 in-reg); V tile staged
// transposed in LDS (Vs[n][k]) so B-frags are contiguous 16B reads.
// ---------------------------------------------------------------------------
__global__ __launch_bounds__(256) void attn_v(
    const float* __restrict__ attn, const unsigned short* __restrict__ Vb,
    float* __restrict__ ctx)
{
  __shared__ unsigned short Vs[64][40];   // Vs[n][k]
  const int tid  = threadIdx.x;
  const int lane = tid & 63, wave = tid >> 6;
  const int quad = lane >> 4, l16 = lane & 15;
  const int wm = (wave >> 1) * 32, wn = (wave & 1) * 32;
  const int q0 = blockIdx.x * 64;
  const int z = blockIdx.y; const int b = z & 3, h = z >> 2;
  const int vk = tid >> 3, vn = (tid & 7) * 8;   // stage 32 k x 64 n

  f32x4 acc[2][2] = {};
  const float* abase = attn + (size_t)z * SS * SS;
  const unsigned short* vbase = Vb + h * DHH;

  for (int k0 = 0; k0 < SS; k0 += 32) {
    u16x8 vv = *(const u16x8*)(vbase + (size_t)(b*SS + k0 + vk) * DD + vn);
    Vs[vn+0][vk]=vv[0]; Vs[vn+1][vk]=vv[1]; Vs[vn+2][vk]=vv[2]; Vs[vn+3][vk]=vv[3];
    Vs[vn+4][vk]=vv[4]; Vs[vn+5][vk]=vv[5]; Vs[vn+6][vk]=vv[6]; Vs[vn+7][vk]=vv[7];
    __syncthreads();

    const float* ap0 = abase + (size_t)(q0+wm   +l16)*SS + k0 + quad*8;
    const float* ap1 = abase + (size_t)(q0+wm+16+l16)*SS + k0 + quad*8;
    float4 x0 = *(const float4*)ap0, x1 = *(const float4*)(ap0 + 4);
    float4 y0 = *(const float4*)ap1, y1 = *(const float4*)(ap1 + 4);
    u16x8 ua, ub;
    ua[0]=f2bf(x0.x); ua[1]=f2bf(x0.y); ua[2]=f2bf(x0.z); ua[3]=f2bf(x0.w);
    ua[4]=f2bf(x1.x); ua[5]=f2bf(x1.y); ua[6]=f2bf(x1.z); ua[7]=f2bf(x1.w);
    ub[0]=f2bf(y0.x); ub[1]=f2bf(y0.y); ub[2]=f2bf(y0.z); ub[3]=f2bf(y0.w);
    ub[4]=f2bf(y1.x); ub[5]=f2bf(y1.y); ub[6]=f2bf(y1.z); ub[7]=f2bf(y1.w);
    bf16x8 a0 = as_bf16x8(ua), a1 = as_bf16x8(ub);

    bf16x8 b0 = as_bf16x8(*(const u16x8*)&Vs[wn      + l16][quad*8]);
    bf16x8 b1 = as_bf16x8(*(const u16x8*)&Vs[wn + 16 + l16][quad*8]);
    acc[0][0] = MFMA(a0, b0, acc[0][0]);
    acc[0][1] = MFMA(a0, b1, acc[0][1]);
    acc[1][0] = MFMA(a1, b0, acc[1][0]);
    acc[1][1] = MFMA(a1, b1, acc[1][1]);
    __syncthreads();
  }

  #pragma unroll
  for (int i = 0; i < 2; i++)
    #pragma unroll
    for (int j = 0; j < 2; j++) {
      const int col = wn + j*16 + l16;              // 0..63 within head
      #pragma unroll
      for (int r = 0; r < 4; r++) {
        const int row = q0 + wm + i*16 + quad*4 + r;
        ctx[(size_t)(b*SS + row) * DD + h*DHH + col] = acc[i][j][r];
      }
    }
}

extern "C" void kernel_launch(void* const* d_in, const int* in_sizes, int n_in,
                              void* d_out, int out_size, void* d_ws, size_t ws_size,
                              hipStream_t stream) {
  const float* query = (const float*)d_in[0];
  const float* key   = (const float*)d_in[1];
  const float* value = (const float*)d_in[2];
  const float* Wq    = (const float*)d_in[3];
  const float* bq    = (const float*)d_in[4];
  const float* Wk    = (const float*)d_in[5];
  const float* bk    = (const float*)d_in[6];
  const float* Wv    = (const float*)d_in[7];
  const float* bv    = (const float*)d_in[8];

  float* ctx  = (float*)d_out;
  float* attn = ctx + (size_t)BB * SS * DD;          // 4,194,304 floats in

  unsigned short* Qb = (unsigned short*)d_ws;        // 3 x 8 MB bf16 in ws
  unsigned short* Kb = Qb + (size_t)MT * DD;
  unsigned short* Vb = Kb + (size_t)MT * DD;

  dim3 g1(MT / 64, DD / 64);                         // 64 x 16
  gemm_xw<<<g1, 256, 0, stream>>>(query, Wq, bq, Qb);
  gemm_xw<<<g1, 256, 0, stream>>>(key,   Wk, bk, Kb);
  gemm_xw<<<g1, 256, 0, stream>>>(value, Wv, bv, Vb);

  dim3 g2(SS / 64, SS / 64, BB * HH);                // 16 x 16 x 64
  qk_scores<<<g2, 256, 0, stream>>>(Qb, Kb, attn);

  softmax_rows<<<(BB * HH * SS) / 4, 256, 0, stream>>>(attn);

  dim3 g4(SS / 64, BB * HH);                         // 16 x 64
  attn_v<<<g4, 256, 0, stream>>>(attn, Vb, ctx);
}

// Round 2
// 521.863 us; speedup vs baseline: 1.3208x; 1.3208x over previous
//
#include <hip/hip_runtime.h>

#define BB 4
#define SS 1024
#define DD 1024
#define HH 16
#define DHH 64
#define MT (BB*SS)   // 4096 rows for QKV projection

typedef __bf16 bf16x8 __attribute__((ext_vector_type(8)));
typedef unsigned short u16x8 __attribute__((ext_vector_type(8)));
typedef float f32x4 __attribute__((ext_vector_type(4)));

__device__ __forceinline__ bf16x8 as_bf16x8(u16x8 u) {
  union { u16x8 u; bf16x8 b; } c; c.u = u; return c.b;
}
__device__ __forceinline__ unsigned short f2bf(float f) {
  unsigned int u = __float_as_uint(f);
  return (unsigned short)((u + 0x7fffu + ((u >> 16) & 1u)) >> 16);
}

#define MFMA(a, b, c) __builtin_amdgcn_mfma_f32_16x16x32_bf16((a), (b), (c), 0, 0, 0)

// ---------------------------------------------------------------------------
// Kernel 1: Out(bf16) = X(MxK fp32) @ W(KxN fp32) + bias.  M=4096,N=K=1024.
// TRANS=0: Out[m][n] row-major (Q, K).
// TRANS=1: Out[n][m] (V transposed: Vt[hd][b*S+s]) via LDS transpose epilogue.
// ---------------------------------------------------------------------------
template <int TRANS>
__global__ __launch_bounds__(256) void gemm_xw(
    const float* __restrict__ X, const float* __restrict__ W,
    const float* __restrict__ bias, unsigned short* __restrict__ Out)
{
  __shared__ unsigned short As[64][40];   // As[m][k]
  __shared__ unsigned short Bs[64][40];   // transposed: Bs[n][k]
  const int tid  = threadIdx.x;
  const int lane = tid & 63, wave = tid >> 6;
  const int quad = lane >> 4, l16 = lane & 15;
  const int wm = (wave >> 1) * 32, wn = (wave & 1) * 32;
  const int m0 = blockIdx.x * 64, n0 = blockIdx.y * 64;
  const int ar = tid >> 2, ac = (tid & 3) * 8;   // A staging: 64 rows x 32 cols
  const int bk = tid >> 3, bn = (tid & 7) * 8;   // B staging: 32 k x 64 n

  f32x4 acc[2][2] = {};

  for (int k0 = 0; k0 < DD; k0 += 32) {
    const float* xa = X + (size_t)(m0 + ar) * DD + k0 + ac;
    float4 a0 = *(const float4*)xa;
    float4 a1 = *(const float4*)(xa + 4);
    const float* wp = W + (size_t)(k0 + bk) * DD + n0 + bn;
    float4 b0 = *(const float4*)wp;
    float4 b1 = *(const float4*)(wp + 4);

    unsigned short* da = &As[ar][ac];
    da[0]=f2bf(a0.x); da[1]=f2bf(a0.y); da[2]=f2bf(a0.z); da[3]=f2bf(a0.w);
    da[4]=f2bf(a1.x); da[5]=f2bf(a1.y); da[6]=f2bf(a1.z); da[7]=f2bf(a1.w);
    Bs[bn+0][bk]=f2bf(b0.x); Bs[bn+1][bk]=f2bf(b0.y);
    Bs[bn+2][bk]=f2bf(b0.z); Bs[bn+3][bk]=f2bf(b0.w);
    Bs[bn+4][bk]=f2bf(b1.x); Bs[bn+5][bk]=f2bf(b1.y);
    Bs[bn+6][bk]=f2bf(b1.z); Bs[bn+7][bk]=f2bf(b1.w);
    __syncthreads();

    bf16x8 af0 = as_bf16x8(*(const u16x8*)&As[wm      + l16][quad*8]);
    bf16x8 af1 = as_bf16x8(*(const u16x8*)&As[wm + 16 + l16][quad*8]);
    bf16x8 bf0 = as_bf16x8(*(const u16x8*)&Bs[wn      + l16][quad*8]);
    bf16x8 bf1 = as_bf16x8(*(const u16x8*)&Bs[wn + 16 + l16][quad*8]);
    acc[0][0] = MFMA(af0, bf0, acc[0][0]);
    acc[0][1] = MFMA(af0, bf1, acc[0][1]);
    acc[1][0] = MFMA(af1, bf0, acc[1][0]);
    acc[1][1] = MFMA(af1, bf1, acc[1][1]);
    __syncthreads();
  }

  if constexpr (TRANS) {
    __shared__ unsigned short Tt[64][72];
    #pragma unroll
    for (int i = 0; i < 2; i++)
      #pragma unroll
      for (int j = 0; j < 2; j++) {
        const float bsv = bias[n0 + wn + j*16 + l16];
        #pragma unroll
        for (int r = 0; r < 4; r++)
          Tt[wm + i*16 + quad*4 + r][wn + j*16 + l16] = f2bf(acc[i][j][r] + bsv);
      }
    __syncthreads();
    const int dd = tid >> 2, s0l = (tid & 3) * 16;
    u16x8 o0, o1;
    #pragma unroll
    for (int e = 0; e < 8; e++) { o0[e] = Tt[s0l + e][dd]; o1[e] = Tt[s0l + 8 + e][dd]; }
    unsigned short* op = Out + (size_t)(n0 + dd) * MT + m0 + s0l;
    *(u16x8*)op = o0;
    *(u16x8*)(op + 8) = o1;
  } else {
    #pragma unroll
    for (int i = 0; i < 2; i++)
      #pragma unroll
      for (int j = 0; j < 2; j++) {
        const int col = n0 + wn + j*16 + l16;
        const float bsv = bias[col];
        #pragma unroll
        for (int r = 0; r < 4; r++) {
          const int row = m0 + wm + i*16 + quad*4 + r;
          Out[(size_t)row * DD + col] = f2bf(acc[i][j][r] + bsv);
        }
      }
  }
}

// ---------------------------------------------------------------------------
// Kernel 2: fused QK^T -> softmax -> attn write -> P@V -> ctx write.
// Block = 256 thr = 4 waves; owns 32 q-rows of one (b,h). Scores (32x1024)
// live in MFMA accumulators: wave w holds cols [w*256, w*256+256).
// Softmax: per-quad shuffle reduce (rows live in 16-lane groups) + LDS
// cross-wave combine. Normalized P: fp32 -> global attn (required output),
// bf16 -> LDS Ps. PV: A-frags from Ps, B-frags from pre-transposed Vt.
// ---------------------------------------------------------------------------
__global__ __launch_bounds__(256, 2) void fused_attn(
    const unsigned short* __restrict__ Qb, const unsigned short* __restrict__ Kb,
    const unsigned short* __restrict__ Vt, float* __restrict__ attn,
    float* __restrict__ ctx)
{
  __shared__ unsigned short Ps[32][1032];   // stride 1032 u16 = 2064 B (16B-aligned rows)
  __shared__ float redm[4][32];
  __shared__ float redl[4][32];

  const int tid  = threadIdx.x;
  const int lane = tid & 63, w = tid >> 6;
  const int quad = lane >> 4, l16 = lane & 15;
  const int q0 = blockIdx.x * 32;
  const int z  = blockIdx.y;             // z = h*B + b (heads-major attn layout)
  const int b = z & 3, h = z >> 2;
  const int cbase = w * 256;

  const unsigned short* qbase = Qb + (size_t)b * SS * DD + h * DHH;
  const unsigned short* kbase = Kb + (size_t)b * SS * DD + h * DHH;

  // Q A-fragments (rows q0 + i*16 + l16, k = kk*32 + quad*8 + j), loaded once.
  bf16x8 aq[2][2];
  #pragma unroll
  for (int i = 0; i < 2; i++)
    #pragma unroll
    for (int kk = 0; kk < 2; kk++)
      aq[i][kk] = as_bf16x8(*(const u16x8*)(
          qbase + (size_t)(q0 + i*16 + l16) * DD + kk*32 + quad*8));

  // ---- Phase 1: scores S = Q K^T (raw, unscaled) ----
  f32x4 acc[2][16] = {};
  #pragma unroll
  for (int t = 0; t < 16; t++) {
    const unsigned short* kp = kbase + (size_t)(cbase + t*16 + l16) * DD + quad*8;
    bf16x8 b0 = as_bf16x8(*(const u16x8*)kp);
    bf16x8 b1 = as_bf16x8(*(const u16x8*)(kp + 32));
    acc[0][t] = MFMA(aq[0][0], b0, acc[0][t]);
    acc[0][t] = MFMA(aq[0][1], b1, acc[0][t]);
    acc[1][t] = MFMA(aq[1][0], b0, acc[1][t]);
    acc[1][t] = MFMA(aq[1][1], b1, acc[1][t]);
  }

  // ---- Phase 2: softmax over each row of 1024 ----
  // Row r = i*16 + quad*4 + rr lives in the 16 lanes {quad*16 .. quad*16+15}.
  float pm[2][4];
  #pragma unroll
  for (int i = 0; i < 2; i++)
    #pragma unroll
    for (int rr = 0; rr < 4; rr++) pm[i][rr] = -3.4e38f;
  #pragma unroll
  for (int i = 0; i < 2; i++)
    #pragma unroll
    for (int t = 0; t < 16; t++)
      #pragma unroll
      for (int rr = 0; rr < 4; rr++) pm[i][rr] = fmaxf(pm[i][rr], acc[i][t][rr]);
  #pragma unroll
  for (int off = 1; off < 16; off <<= 1)
    #pragma unroll
    for (int i = 0; i < 2; i++)
      #pragma unroll
      for (int rr = 0; rr < 4; rr++)
        pm[i][rr] = fmaxf(pm[i][rr], __shfl_xor(pm[i][rr], off));
  if (l16 == 0) {
    #pragma unroll
    for (int i = 0; i < 2; i++)
      #pragma unroll
      for (int rr = 0; rr < 4; rr++)
        redm[w][i*16 + quad*4 + rr] = pm[i][rr];
  }
  __syncthreads();
  float cc[2][4];
  #pragma unroll
  for (int i = 0; i < 2; i++)
    #pragma unroll
    for (int rr = 0; rr < 4; rr++) {
      const int r = i*16 + quad*4 + rr;
      float m = fmaxf(fmaxf(redm[0][r], redm[1][r]), fmaxf(redm[2][r], redm[3][r]));
      cc[i][rr] = m * 0.125f;
    }

  float ps[2][4] = {};
  #pragma unroll
  for (int i = 0; i < 2; i++)
    #pragma unroll
    for (int t = 0; t < 16; t++)
      #pragma unroll
      for (int rr = 0; rr < 4; rr++) {
        float e = __expf(fmaf(acc[i][t][rr], 0.125f, -cc[i][rr]));
        acc[i][t][rr] = e;
        ps[i][rr] += e;
      }
  #pragma unroll
  for (int off = 1; off < 16; off <<= 1)
    #pragma unroll
    for (int i = 0; i < 2; i++)
      #pragma unroll
      for (int rr = 0; rr < 4; rr++)
        ps[i][rr] += __shfl_xor(ps[i][rr], off);
  if (l16 == 0) {
    #pragma unroll
    for (int i = 0; i < 2; i++)
      #pragma unroll
      for (int rr = 0; rr < 4; rr++)
        redl[w][i*16 + quad*4 + rr] = ps[i][rr];
  }
  __syncthreads();
  float inv[2][4];
  #pragma unroll
  for (int i = 0; i < 2; i++)
    #pragma unroll
    for (int rr = 0; rr < 4; rr++) {
      const int r = i*16 + quad*4 + rr;
      inv[i][rr] = 1.0f / (redl[0][r] + redl[1][r] + redl[2][r] + redl[3][r]);
    }

  // ---- Phase 3+4: write normalized attn (fp32, global) + P (bf16, LDS) ----
  float* obase = attn + (size_t)z * SS * SS;
  #pragma unroll
  for (int i = 0; i < 2; i++)
    #pragma unroll
    for (int t = 0; t < 16; t++) {
      const int col = cbase + t*16 + l16;
      #pragma unroll
      for (int rr = 0; rr < 4; rr++) {
        const int row = i*16 + quad*4 + rr;
        float p = acc[i][t][rr] * inv[i][rr];
        obase[(size_t)(q0 + row) * SS + col] = p;
        Ps[row][col] = f2bf(p);
      }
    }
  __syncthreads();

  // ---- Phase 5: ctx = P @ V  (M=32, N=64, K=1024); wave w -> dh cols w*16.. ----
  const unsigned short* vbase = Vt + (size_t)(h*DHH + w*16 + l16) * MT + b*SS + quad*8;
  f32x4 accp[2] = {};
  #pragma unroll 8
  for (int ks = 0; ks < 32; ks++) {
    bf16x8 bv = as_bf16x8(*(const u16x8*)(vbase + ks*32));
    bf16x8 a0 = as_bf16x8(*(const u16x8*)&Ps[l16][ks*32 + quad*8]);
    bf16x8 a1 = as_bf16x8(*(const u16x8*)&Ps[16 + l16][ks*32 + quad*8]);
    accp[0] = MFMA(a0, bv, accp[0]);
    accp[1] = MFMA(a1, bv, accp[1]);
  }
  #pragma unroll
  for (int i = 0; i < 2; i++)
    #pragma unroll
    for (int rr = 0; rr < 4; rr++)
      ctx[(size_t)(b*SS + q0 + i*16 + quad*4 + rr) * DD + h*DHH + w*16 + l16] =
          accp[i][rr];
}

extern "C" void kernel_launch(void* const* d_in, const int* in_sizes, int n_in,
                              void* d_out, int out_size, void* d_ws, size_t ws_size,
                              hipStream_t stream) {
  const float* query = (const float*)d_in[0];
  const float* key   = (const float*)d_in[1];
  const float* value = (const float*)d_in[2];
  const float* Wq    = (const float*)d_in[3];
  const float* bq    = (const float*)d_in[4];
  const float* Wk    = (const float*)d_in[5];
  const float* bk    = (const float*)d_in[6];
  const float* Wv    = (const float*)d_in[7];
  const float* bv    = (const float*)d_in[8];

  float* ctx  = (float*)d_out;
  float* attn = ctx + (size_t)BB * SS * DD;

  unsigned short* Qb = (unsigned short*)d_ws;        // 8 MB
  unsigned short* Kb = Qb + (size_t)MT * DD;         // 8 MB
  unsigned short* Vt = Kb + (size_t)MT * DD;         // 8 MB, layout [hd][b*S+s]

  dim3 g1(MT / 64, DD / 64);                         // 64 x 16
  gemm_xw<0><<<g1, 256, 0, stream>>>(query, Wq, bq, Qb);
  gemm_xw<0><<<g1, 256, 0, stream>>>(key,   Wk, bk, Kb);
  gemm_xw<1><<<g1, 256, 0, stream>>>(value, Wv, bv, Vt);

  dim3 g2(SS / 32, BB * HH);                         // 32 x 64
  fused_attn<<<g2, 256, 0, stream>>>(Qb, Kb, Vt, attn, ctx);
}

// Round 3
// 475.515 us; speedup vs baseline: 1.4495x; 1.0975x over previous
//
#include <hip/hip_runtime.h>

#define BB 4
#define SS 1024
#define DD 1024
#define HH 16
#define DHH 64
#define MT (BB*SS)   // 4096 rows for QKV projection

typedef __bf16 bf16x8 __attribute__((ext_vector_type(8)));
typedef unsigned short u16x8 __attribute__((ext_vector_type(8)));
typedef float f32x4 __attribute__((ext_vector_type(4)));

__device__ __forceinline__ bf16x8 as_bf16x8(u16x8 u) {
  union { u16x8 u; bf16x8 b; } c; c.u = u; return c.b;
}
__device__ __forceinline__ unsigned short f2bf(float f) {
  unsigned int u = __float_as_uint(f);
  return (unsigned short)((u + 0x7fffu + ((u >> 16) & 1u)) >> 16);
}

#define MFMA(a, b, c) __builtin_amdgcn_mfma_f32_16x16x32_bf16((a), (b), (c), 0, 0, 0)

typedef const __attribute__((address_space(1))) unsigned int* gas1;
typedef __attribute__((address_space(3))) unsigned int* las3;
__device__ __forceinline__ void gl_lds16(const void* g, void* l) {
  __builtin_amdgcn_global_load_lds((gas1)g, (las3)l, 16, 0, 0);
}

// ---------------------------------------------------------------------------
// conv_x: fp32 -> bf16, 4M elements, 8/thread.
// ---------------------------------------------------------------------------
__global__ __launch_bounds__(256) void conv_x(
    const float* __restrict__ in, unsigned short* __restrict__ out)
{
  const int i = (blockIdx.x * 256 + threadIdx.x) * 8;
  float4 x0 = *(const float4*)(in + i);
  float4 x1 = *(const float4*)(in + i + 4);
  u16x8 o;
  o[0]=f2bf(x0.x); o[1]=f2bf(x0.y); o[2]=f2bf(x0.z); o[3]=f2bf(x0.w);
  o[4]=f2bf(x1.x); o[5]=f2bf(x1.y); o[6]=f2bf(x1.z); o[7]=f2bf(x1.w);
  *(u16x8*)(out + i) = o;
}

// ---------------------------------------------------------------------------
// conv_wT: W (K x N fp32, row-major) -> Wt (N x K bf16). 64x64 LDS tiles.
// ---------------------------------------------------------------------------
__global__ __launch_bounds__(256) void conv_wT(
    const float* __restrict__ W, unsigned short* __restrict__ Wt)
{
  __shared__ unsigned short Ts[64][72];
  const int tid = threadIdx.x;
  const int n0 = blockIdx.x * 64, k0 = blockIdx.y * 64;
  const int r = tid >> 2, cs = (tid & 3) * 16;
  const float* wp = W + (size_t)(k0 + r) * DD + n0 + cs;
  #pragma unroll
  for (int c = 0; c < 4; c++) {
    float4 x = *(const float4*)(wp + c*4);
    Ts[r][cs + c*4 + 0] = f2bf(x.x); Ts[r][cs + c*4 + 1] = f2bf(x.y);
    Ts[r][cs + c*4 + 2] = f2bf(x.z); Ts[r][cs + c*4 + 3] = f2bf(x.w);
  }
  __syncthreads();
  const int nl = tid >> 2, ks = (tid & 3) * 16;
  u16x8 o0, o1;
  #pragma unroll
  for (int e = 0; e < 8; e++) { o0[e] = Ts[ks + e][nl]; o1[e] = Ts[ks + 8 + e][nl]; }
  unsigned short* op = Wt + (size_t)(n0 + nl) * DD + k0 + ks;
  *(u16x8*)op = o0;
  *(u16x8*)(op + 8) = o1;
}

// ---------------------------------------------------------------------------
// gemm_bt: Out = A(4096xK bf16) @ Bt(NxK bf16)^T + bias, m97-style.
// BM=128, BN=64, BK=64. 256 thr = 4 waves (2x2), wave tile 64x32 (4x2 MFMA).
// Staging via global_load_lds width=16 (no VALU, no VGPR round-trip).
// TRANS=0: Out[m][n] row-major bf16.  TRANS=1: Out[n][m] (Vt) via LDS xpose.
// ---------------------------------------------------------------------------
template <int TRANS>
__global__ __launch_bounds__(256) void gemm_bt(
    const unsigned short* __restrict__ A, const unsigned short* __restrict__ Bt,
    const float* __restrict__ bias, unsigned short* __restrict__ Out)
{
  __shared__ union {
    struct { unsigned short A[128 * 64]; unsigned short B[64 * 64]; } s;
    unsigned short T[64][136];   // transpose scratch (TRANS=1 epilogue)
  } sm;

  const int tid  = threadIdx.x;
  const int lane = tid & 63, wave = tid >> 6;
  const int quad = lane >> 4, l16 = lane & 15;
  const int wm = (wave >> 1) * 64, wn = (wave & 1) * 32;
  const int m0 = blockIdx.x * 128, n0 = blockIdx.y * 64;
  const int lrow = lane >> 3, lcol = (lane & 7) * 8;   // within an 8-row chunk

  f32x4 acc[4][2] = {};

  for (int k0 = 0; k0 < DD; k0 += 64) {
    // stage A: 16 chunks of 8 rows; wave w handles chunks w*4 .. w*4+3
    #pragma unroll
    for (int r = 0; r < 4; r++) {
      const int c = wave * 4 + r;
      gl_lds16(A + (size_t)(m0 + c*8 + lrow) * DD + k0 + lcol,
               &sm.s.A[c * 512]);        // c*1024 bytes
    }
    // stage B: 8 chunks; wave w handles chunks w*2 .. w*2+1
    #pragma unroll
    for (int r = 0; r < 2; r++) {
      const int c = wave * 2 + r;
      gl_lds16(Bt + (size_t)(n0 + c*8 + lrow) * DD + k0 + lcol,
               &sm.s.B[c * 512]);
    }
    __syncthreads();

    #pragma unroll
    for (int ks = 0; ks < 2; ks++) {
      bf16x8 af[4], bf[2];
      #pragma unroll
      for (int i = 0; i < 4; i++)
        af[i] = as_bf16x8(*(const u16x8*)&sm.s.A[(wm + i*16 + l16)*64 + ks*32 + quad*8]);
      #pragma unroll
      for (int j = 0; j < 2; j++)
        bf[j] = as_bf16x8(*(const u16x8*)&sm.s.B[(wn + j*16 + l16)*64 + ks*32 + quad*8]);
      #pragma unroll
      for (int i = 0; i < 4; i++)
        #pragma unroll
        for (int j = 0; j < 2; j++)
          acc[i][j] = MFMA(af[i], bf[j], acc[i][j]);
    }
    __syncthreads();
  }

  if constexpr (TRANS) {
    // write acc into Tt[n_local][m_local], then coalesced store of Vt rows
    #pragma unroll
    for (int j = 0; j < 2; j++) {
      const float bsv = bias[n0 + wn + j*16 + l16];
      #pragma unroll
      for (int i = 0; i < 4; i++)
        #pragma unroll
        for (int r = 0; r < 4; r++)
          sm.T[wn + j*16 + l16][wm + i*16 + quad*4 + r] = f2bf(acc[i][j][r] + bsv);
    }
    __syncthreads();
    const int nl = tid >> 2, mq = (tid & 3) * 32;
    unsigned short* op = Out + (size_t)(n0 + nl) * MT + m0 + mq;
    #pragma unroll
    for (int e = 0; e < 4; e++)
      *(u16x8*)(op + e*8) = *(const u16x8*)&sm.T[nl][mq + e*8];
  } else {
    #pragma unroll
    for (int j = 0; j < 2; j++) {
      const int col = n0 + wn + j*16 + l16;
      const float bsv = bias[col];
      #pragma unroll
      for (int i = 0; i < 4; i++) {
        #pragma unroll
        for (int r = 0; r < 4; r++) {
          const int row = m0 + wm + i*16 + quad*4 + r;
          Out[(size_t)row * DD + col] = f2bf(acc[i][j][r] + bsv);
        }
      }
    }
  }
}

// ---------------------------------------------------------------------------
// fused QK^T -> softmax -> attn write -> P@V -> ctx write (unchanged from R2)
// ---------------------------------------------------------------------------
__global__ __launch_bounds__(256, 2) void fused_attn(
    const unsigned short* __restrict__ Qb, const unsigned short* __restrict__ Kb,
    const unsigned short* __restrict__ Vt, float* __restrict__ attn,
    float* __restrict__ ctx)
{
  __shared__ unsigned short Ps[32][1032];
  __shared__ float redm[4][32];
  __shared__ float redl[4][32];

  const int tid  = threadIdx.x;
  const int lane = tid & 63, w = tid >> 6;
  const int quad = lane >> 4, l16 = lane & 15;
  const int q0 = blockIdx.x * 32;
  const int z  = blockIdx.y;
  const int b = z & 3, h = z >> 2;
  const int cbase = w * 256;

  const unsigned short* qbase = Qb + (size_t)b * SS * DD + h * DHH;
  const unsigned short* kbase = Kb + (size_t)b * SS * DD + h * DHH;

  bf16x8 aq[2][2];
  #pragma unroll
  for (int i = 0; i < 2; i++)
    #pragma unroll
    for (int kk = 0; kk < 2; kk++)
      aq[i][kk] = as_bf16x8(*(const u16x8*)(
          qbase + (size_t)(q0 + i*16 + l16) * DD + kk*32 + quad*8));

  f32x4 acc[2][16] = {};
  #pragma unroll
  for (int t = 0; t < 16; t++) {
    const unsigned short* kp = kbase + (size_t)(cbase + t*16 + l16) * DD + quad*8;
    bf16x8 b0 = as_bf16x8(*(const u16x8*)kp);
    bf16x8 b1 = as_bf16x8(*(const u16x8*)(kp + 32));
    acc[0][t] = MFMA(aq[0][0], b0, acc[0][t]);
    acc[0][t] = MFMA(aq[0][1], b1, acc[0][t]);
    acc[1][t] = MFMA(aq[1][0], b0, acc[1][t]);
    acc[1][t] = MFMA(aq[1][1], b1, acc[1][t]);
  }

  float pm[2][4];
  #pragma unroll
  for (int i = 0; i < 2; i++)
    #pragma unroll
    for (int rr = 0; rr < 4; rr++) pm[i][rr] = -3.4e38f;
  #pragma unroll
  for (int i = 0; i < 2; i++)
    #pragma unroll
    for (int t = 0; t < 16; t++)
      #pragma unroll
      for (int rr = 0; rr < 4; rr++) pm[i][rr] = fmaxf(pm[i][rr], acc[i][t][rr]);
  #pragma unroll
  for (int off = 1; off < 16; off <<= 1)
    #pragma unroll
    for (int i = 0; i < 2; i++)
      #pragma unroll
      for (int rr = 0; rr < 4; rr++)
        pm[i][rr] = fmaxf(pm[i][rr], __shfl_xor(pm[i][rr], off));
  if (l16 == 0) {
    #pragma unroll
    for (int i = 0; i < 2; i++)
      #pragma unroll
      for (int rr = 0; rr < 4; rr++)
        redm[w][i*16 + quad*4 + rr] = pm[i][rr];
  }
  __syncthreads();
  float cc[2][4];
  #pragma unroll
  for (int i = 0; i < 2; i++)
    #pragma unroll
    for (int rr = 0; rr < 4; rr++) {
      const int r = i*16 + quad*4 + rr;
      float m = fmaxf(fmaxf(redm[0][r], redm[1][r]), fmaxf(redm[2][r], redm[3][r]));
      cc[i][rr] = m * 0.125f;
    }

  float ps[2][4] = {};
  #pragma unroll
  for (int i = 0; i < 2; i++)
    #pragma unroll
    for (int t = 0; t < 16; t++)
      #pragma unroll
      for (int rr = 0; rr < 4; rr++) {
        float e = __expf(fmaf(acc[i][t][rr], 0.125f, -cc[i][rr]));
        acc[i][t][rr] = e;
        ps[i][rr] += e;
      }
  #pragma unroll
  for (int off = 1; off < 16; off <<= 1)
    #pragma unroll
    for (int i = 0; i < 2; i++)
      #pragma unroll
      for (int rr = 0; rr < 4; rr++)
        ps[i][rr] += __shfl_xor(ps[i][rr], off);
  if (l16 == 0) {
    #pragma unroll
    for (int i = 0; i < 2; i++)
      #pragma unroll
      for (int rr = 0; rr < 4; rr++)
        redl[w][i*16 + quad*4 + rr] = ps[i][rr];
  }
  __syncthreads();
  float inv[2][4];
  #pragma unroll
  for (int i = 0; i < 2; i++)
    #pragma unroll
    for (int rr = 0; rr < 4; rr++) {
      const int r = i*16 + quad*4 + rr;
      inv[i][rr] = 1.0f / (redl[0][r] + redl[1][r] + redl[2][r] + redl[3][r]);
    }

  float* obase = attn + (size_t)z * SS * SS;
  #pragma unroll
  for (int i = 0; i < 2; i++)
    #pragma unroll
    for (int t = 0; t < 16; t++) {
      const int col = cbase + t*16 + l16;
      #pragma unroll
      for (int rr = 0; rr < 4; rr++) {
        const int row = i*16 + quad*4 + rr;
        float p = acc[i][t][rr] * inv[i][rr];
        obase[(size_t)(q0 + row) * SS + col] = p;
        Ps[row][col] = f2bf(p);
      }
    }
  __syncthreads();

  const unsigned short* vbase = Vt + (size_t)(h*DHH + w*16 + l16) * MT + b*SS + quad*8;
  f32x4 accp[2] = {};
  #pragma unroll 8
  for (int ks = 0; ks < 32; ks++) {
    bf16x8 bv = as_bf16x8(*(const u16x8*)(vbase + ks*32));
    bf16x8 a0 = as_bf16x8(*(const u16x8*)&Ps[l16][ks*32 + quad*8]);
    bf16x8 a1 = as_bf16x8(*(const u16x8*)&Ps[16 + l16][ks*32 + quad*8]);
    accp[0] = MFMA(a0, bv, accp[0]);
    accp[1] = MFMA(a1, bv, accp[1]);
  }
  #pragma unroll
  for (int i = 0; i < 2; i++)
    #pragma unroll
    for (int rr = 0; rr < 4; rr++)
      ctx[(size_t)(b*SS + q0 + i*16 + quad*4 + rr) * DD + h*DHH + w*16 + l16] =
          accp[i][rr];
}

extern "C" void kernel_launch(void* const* d_in, const int* in_sizes, int n_in,
                              void* d_out, int out_size, void* d_ws, size_t ws_size,
                              hipStream_t stream) {
  const float* query = (const float*)d_in[0];
  const float* key   = (const float*)d_in[1];
  const float* value = (const float*)d_in[2];
  const float* Wq    = (const float*)d_in[3];
  const float* bq    = (const float*)d_in[4];
  const float* Wk    = (const float*)d_in[5];
  const float* bk    = (const float*)d_in[6];
  const float* Wv    = (const float*)d_in[7];
  const float* bv    = (const float*)d_in[8];

  float* ctx  = (float*)d_out;
  float* attn = ctx + (size_t)BB * SS * DD;

  unsigned short* Qb  = (unsigned short*)d_ws;       // 8 MB
  unsigned short* Kb  = Qb + (size_t)MT * DD;        // 8 MB
  unsigned short* Vt  = Kb + (size_t)MT * DD;        // 8 MB  [hd][b*S+s]
  unsigned short* Xb  = Vt + (size_t)MT * DD;        // 8 MB  (serially reused)
  unsigned short* Wtb = Xb + (size_t)MT * DD;        // 2 MB  (serially reused)

  dim3 gc(MT * DD / (256 * 8));                      // 2048 blocks
  dim3 gw(DD / 64, DD / 64);                         // 16 x 16
  dim3 gg(MT / 128, DD / 64);                        // 32 x 16 -> 512 blocks

  conv_x <<<gc, 256, 0, stream>>>(query, Xb);
  conv_wT<<<gw, 256, 0, stream>>>(Wq, Wtb);
  gemm_bt<0><<<gg, 256, 0, stream>>>(Xb, Wtb, bq, Qb);

  conv_x <<<gc, 256, 0, stream>>>(key, Xb);
  conv_wT<<<gw, 256, 0, stream>>>(Wk, Wtb);
  gemm_bt<0><<<gg, 256, 0, stream>>>(Xb, Wtb, bk, Kb);

  conv_x <<<gc, 256, 0, stream>>>(value, Xb);
  conv_wT<<<gw, 256, 0, stream>>>(Wv, Wtb);
  gemm_bt<1><<<gg, 256, 0, stream>>>(Xb, Wtb, bv, Vt);

  dim3 g2(SS / 32, BB * HH);                         // 32 x 64
  fused_attn<<<g2, 256, 0, stream>>>(Qb, Kb, Vt, attn, ctx);
}

// Round 4
// 453.352 us; speedup vs baseline: 1.5204x; 1.0489x over previous
//
#include <hip/hip_runtime.h>

#define BB 4
#define SS 1024
#define DD 1024
#define HH 16
#define DHH 64
#define MT (BB*SS)   // 4096 rows for QKV projection

typedef __bf16 bf16x8 __attribute__((ext_vector_type(8)));
typedef unsigned short u16x8 __attribute__((ext_vector_type(8)));
typedef unsigned short u16x4 __attribute__((ext_vector_type(4)));
typedef float f32x4 __attribute__((ext_vector_type(4)));

__device__ __forceinline__ bf16x8 as_bf16x8(u16x8 u) {
  union { u16x8 u; bf16x8 b; } c; c.u = u; return c.b;
}
__device__ __forceinline__ unsigned short f2bf(float f) {
  unsigned int u = __float_as_uint(f);
  return (unsigned short)((u + 0x7fffu + ((u >> 16) & 1u)) >> 16);
}
__device__ __forceinline__ float bf2f(unsigned short u) {
  return __uint_as_float((unsigned int)u << 16);
}

#define MFMA(a, b, c) __builtin_amdgcn_mfma_f32_16x16x32_bf16((a), (b), (c), 0, 0, 0)

typedef const __attribute__((address_space(1))) unsigned int* gas1;
typedef __attribute__((address_space(3))) unsigned int* las3;
__device__ __forceinline__ void gl_lds16(const void* g, void* l) {
  __builtin_amdgcn_global_load_lds((gas1)g, (las3)l, 16, 0, 0);
}

// ---------------------------------------------------------------------------
// conv_x3: fp32 -> bf16 for query/key/value in one dispatch (z picks input).
// ---------------------------------------------------------------------------
__global__ __launch_bounds__(256) void conv_x3(
    const float* __restrict__ q, const float* __restrict__ k,
    const float* __restrict__ v, unsigned short* __restrict__ out)
{
  const int zz = blockIdx.y;
  const float* in = (zz == 0) ? q : (zz == 1) ? k : v;
  unsigned short* o = out + (size_t)zz * MT * DD;
  const int i = (blockIdx.x * 256 + threadIdx.x) * 8;
  float4 x0 = *(const float4*)(in + i);
  float4 x1 = *(const float4*)(in + i + 4);
  u16x8 r;
  r[0]=f2bf(x0.x); r[1]=f2bf(x0.y); r[2]=f2bf(x0.z); r[3]=f2bf(x0.w);
  r[4]=f2bf(x1.x); r[5]=f2bf(x1.y); r[6]=f2bf(x1.z); r[7]=f2bf(x1.w);
  *(u16x8*)(o + i) = r;
}

// ---------------------------------------------------------------------------
// conv_wT3: W (K x N fp32) -> Wt (N x K bf16) for Wq/Wk/Wv in one dispatch.
// ---------------------------------------------------------------------------
__global__ __launch_bounds__(256) void conv_wT3(
    const float* __restrict__ wq, const float* __restrict__ wk,
    const float* __restrict__ wv, unsigned short* __restrict__ out)
{
  __shared__ unsigned short Ts[64][72];
  const int zz = blockIdx.z;
  const float* W = (zz == 0) ? wq : (zz == 1) ? wk : wv;
  unsigned short* Wt = out + (size_t)zz * DD * DD;
  const int tid = threadIdx.x;
  const int n0 = blockIdx.x * 64, k0 = blockIdx.y * 64;
  const int r = tid >> 2, cs = (tid & 3) * 16;
  const float* wp = W + (size_t)(k0 + r) * DD + n0 + cs;
  #pragma unroll
  for (int c = 0; c < 4; c++) {
    float4 x = *(const float4*)(wp + c*4);
    Ts[r][cs + c*4 + 0] = f2bf(x.x); Ts[r][cs + c*4 + 1] = f2bf(x.y);
    Ts[r][cs + c*4 + 2] = f2bf(x.z); Ts[r][cs + c*4 + 3] = f2bf(x.w);
  }
  __syncthreads();
  const int nl = tid >> 2, ks = (tid & 3) * 16;
  u16x8 o0, o1;
  #pragma unroll
  for (int e = 0; e < 8; e++) { o0[e] = Ts[ks + e][nl]; o1[e] = Ts[ks + 8 + e][nl]; }
  unsigned short* op = Wt + (size_t)(n0 + nl) * DD + k0 + ks;
  *(u16x8*)op = o0;
  *(u16x8*)(op + 8) = o1;
}

// ---------------------------------------------------------------------------
// gemm3: all three projections in ONE dispatch (grid.z = 3 -> 1536 blocks).
// Out = A(4096xK) @ Bt(NxK)^T + bias. BM=128, BN=64, BK=64, 4 waves (2x2),
// wave tile 64x32. Staging via global_load_lds width=16.
// z=0 -> Qb row-major, z=1 -> Kb row-major, z=2 -> Vt transposed.
// ---------------------------------------------------------------------------
__global__ __launch_bounds__(256) void gemm3(
    const unsigned short* __restrict__ X3, const unsigned short* __restrict__ Wt3,
    const float* __restrict__ bq, const float* __restrict__ bk,
    const float* __restrict__ bv, unsigned short* __restrict__ Qb,
    unsigned short* __restrict__ Kb, unsigned short* __restrict__ Vt)
{
  __shared__ union {
    struct { unsigned short A[128 * 64]; unsigned short B[64 * 64]; } s;
    unsigned short T[64][136];
  } sm;

  const int zz = blockIdx.z;
  const unsigned short* A  = X3  + (size_t)zz * MT * DD;
  const unsigned short* Bt = Wt3 + (size_t)zz * DD * DD;
  const float* bias = (zz == 0) ? bq : (zz == 1) ? bk : bv;

  const int tid  = threadIdx.x;
  const int lane = tid & 63, wave = tid >> 6;
  const int quad = lane >> 4, l16 = lane & 15;
  const int wm = (wave >> 1) * 64, wn = (wave & 1) * 32;
  const int m0 = blockIdx.x * 128, n0 = blockIdx.y * 64;
  const int lrow = lane >> 3, lcol = (lane & 7) * 8;

  f32x4 acc[4][2] = {};

  for (int k0 = 0; k0 < DD; k0 += 64) {
    #pragma unroll
    for (int r = 0; r < 4; r++) {
      const int c = wave * 4 + r;
      gl_lds16(A + (size_t)(m0 + c*8 + lrow) * DD + k0 + lcol, &sm.s.A[c * 512]);
    }
    #pragma unroll
    for (int r = 0; r < 2; r++) {
      const int c = wave * 2 + r;
      gl_lds16(Bt + (size_t)(n0 + c*8 + lrow) * DD + k0 + lcol, &sm.s.B[c * 512]);
    }
    __syncthreads();

    #pragma unroll
    for (int ks = 0; ks < 2; ks++) {
      bf16x8 af[4], bf[2];
      #pragma unroll
      for (int i = 0; i < 4; i++)
        af[i] = as_bf16x8(*(const u16x8*)&sm.s.A[(wm + i*16 + l16)*64 + ks*32 + quad*8]);
      #pragma unroll
      for (int j = 0; j < 2; j++)
        bf[j] = as_bf16x8(*(const u16x8*)&sm.s.B[(wn + j*16 + l16)*64 + ks*32 + quad*8]);
      #pragma unroll
      for (int i = 0; i < 4; i++)
        #pragma unroll
        for (int j = 0; j < 2; j++)
          acc[i][j] = MFMA(af[i], bf[j], acc[i][j]);
    }
    __syncthreads();
  }

  if (zz == 2) {
    #pragma unroll
    for (int j = 0; j < 2; j++) {
      const float bsv = bias[n0 + wn + j*16 + l16];
      #pragma unroll
      for (int i = 0; i < 4; i++)
        #pragma unroll
        for (int r = 0; r < 4; r++)
          sm.T[wn + j*16 + l16][wm + i*16 + quad*4 + r] = f2bf(acc[i][j][r] + bsv);
    }
    __syncthreads();
    const int nl = tid >> 2, mq = (tid & 3) * 32;
    unsigned short* op = Vt + (size_t)(n0 + nl) * MT + m0 + mq;
    #pragma unroll
    for (int e = 0; e < 4; e++)
      *(u16x8*)(op + e*8) = *(const u16x8*)&sm.T[nl][mq + e*8];
  } else {
    unsigned short* Out = (zz == 0) ? Qb : Kb;
    #pragma unroll
    for (int j = 0; j < 2; j++) {
      const int col = n0 + wn + j*16 + l16;
      const float bsv = bias[col];
      #pragma unroll
      for (int i = 0; i < 4; i++)
        #pragma unroll
        for (int r = 0; r < 4; r++) {
          const int row = m0 + wm + i*16 + quad*4 + r;
          Out[(size_t)row * DD + col] = f2bf(acc[i][j][r] + bsv);
        }
    }
  }
}

// ---------------------------------------------------------------------------
// fused QK^T -> softmax -> P(bf16) in LDS -> coalesced fp32 attn store -> P@V.
// Block = 4 waves, owns 32 q-rows of one (b,h); wave w holds score cols
// [w*256, w*256+256) in 128 VGPRs of accumulators.
// ---------------------------------------------------------------------------
__global__ __launch_bounds__(256, 2) void fused_attn(
    const unsigned short* __restrict__ Qb, const unsigned short* __restrict__ Kb,
    const unsigned short* __restrict__ Vt, float* __restrict__ attn,
    float* __restrict__ ctx)
{
  __shared__ unsigned short Ps[32][1032];
  __shared__ float redm[4][32];
  __shared__ float redl[4][32];

  const int tid  = threadIdx.x;
  const int lane = tid & 63, w = tid >> 6;
  const int quad = lane >> 4, l16 = lane & 15;
  const int q0 = blockIdx.x * 32;
  const int z  = blockIdx.y;             // z = h*B + b
  const int b = z & 3, h = z >> 2;
  const int cbase = w * 256;

  const unsigned short* qbase = Qb + (size_t)b * SS * DD + h * DHH;
  const unsigned short* kbase = Kb + (size_t)b * SS * DD + h * DHH;

  bf16x8 aq[2][2];
  #pragma unroll
  for (int i = 0; i < 2; i++)
    #pragma unroll
    for (int kk = 0; kk < 2; kk++)
      aq[i][kk] = as_bf16x8(*(const u16x8*)(
          qbase + (size_t)(q0 + i*16 + l16) * DD + kk*32 + quad*8));

  // ---- Phase 1: S = Q K^T ----
  f32x4 acc[2][16] = {};
  #pragma unroll
  for (int t = 0; t < 16; t++) {
    const unsigned short* kp = kbase + (size_t)(cbase + t*16 + l16) * DD + quad*8;
    bf16x8 b0 = as_bf16x8(*(const u16x8*)kp);
    bf16x8 b1 = as_bf16x8(*(const u16x8*)(kp + 32));
    acc[0][t] = MFMA(aq[0][0], b0, acc[0][t]);
    acc[0][t] = MFMA(aq[0][1], b1, acc[0][t]);
    acc[1][t] = MFMA(aq[1][0], b0, acc[1][t]);
    acc[1][t] = MFMA(aq[1][1], b1, acc[1][t]);
  }

  // ---- Phase 2: softmax ----
  float pm[2][4];
  #pragma unroll
  for (int i = 0; i < 2; i++)
    #pragma unroll
    for (int rr = 0; rr < 4; rr++) pm[i][rr] = -3.4e38f;
  #pragma unroll
  for (int i = 0; i < 2; i++)
    #pragma unroll
    for (int t = 0; t < 16; t++)
      #pragma unroll
      for (int rr = 0; rr < 4; rr++) pm[i][rr] = fmaxf(pm[i][rr], acc[i][t][rr]);
  #pragma unroll
  for (int off = 1; off < 16; off <<= 1)
    #pragma unroll
    for (int i = 0; i < 2; i++)
      #pragma unroll
      for (int rr = 0; rr < 4; rr++)
        pm[i][rr] = fmaxf(pm[i][rr], __shfl_xor(pm[i][rr], off));
  if (l16 == 0) {
    #pragma unroll
    for (int i = 0; i < 2; i++)
      #pragma unroll
      for (int rr = 0; rr < 4; rr++)
        redm[w][i*16 + quad*4 + rr] = pm[i][rr];
  }
  __syncthreads();
  float cc[2][4];
  #pragma unroll
  for (int i = 0; i < 2; i++)
    #pragma unroll
    for (int rr = 0; rr < 4; rr++) {
      const int r = i*16 + quad*4 + rr;
      float m = fmaxf(fmaxf(redm[0][r], redm[1][r]), fmaxf(redm[2][r], redm[3][r]));
      cc[i][rr] = m * 0.125f;
    }

  float ps[2][4] = {};
  #pragma unroll
  for (int i = 0; i < 2; i++)
    #pragma unroll
    for (int t = 0; t < 16; t++)
      #pragma unroll
      for (int rr = 0; rr < 4; rr++) {
        float e = __expf(fmaf(acc[i][t][rr], 0.125f, -cc[i][rr]));
        acc[i][t][rr] = e;
        ps[i][rr] += e;
      }
  #pragma unroll
  for (int off = 1; off < 16; off <<= 1)
    #pragma unroll
    for (int i = 0; i < 2; i++)
      #pragma unroll
      for (int rr = 0; rr < 4; rr++)
        ps[i][rr] += __shfl_xor(ps[i][rr], off);
  if (l16 == 0) {
    #pragma unroll
    for (int i = 0; i < 2; i++)
      #pragma unroll
      for (int rr = 0; rr < 4; rr++)
        redl[w][i*16 + quad*4 + rr] = ps[i][rr];
  }
  __syncthreads();
  float inv[2][4];
  #pragma unroll
  for (int i = 0; i < 2; i++)
    #pragma unroll
    for (int rr = 0; rr < 4; rr++) {
      const int r = i*16 + quad*4 + rr;
      inv[i][rr] = 1.0f / (redl[0][r] + redl[1][r] + redl[2][r] + redl[3][r]);
    }

  // ---- Phase 3: normalized P (bf16) into LDS ----
  #pragma unroll
  for (int i = 0; i < 2; i++)
    #pragma unroll
    for (int t = 0; t < 16; t++) {
      const int col = cbase + t*16 + l16;
      #pragma unroll
      for (int rr = 0; rr < 4; rr++)
        Ps[i*16 + quad*4 + rr][col] = f2bf(acc[i][t][rr] * inv[i][rr]);
    }
  __syncthreads();

  // ---- Phase 4: coalesced fp32 attn store from Ps (32x1024 contiguous slab)
  float* slab = attn + ((size_t)z * SS + q0) * SS;
  #pragma unroll 4
  for (int j = 0; j < 32; j++) {
    const int c = j * 256 + tid;           // float4 chunk index, 0..8191
    const int row = c >> 8, col4 = (c & 255) * 4;
    u16x4 pv = *(const u16x4*)&Ps[row][col4];
    float4 o;
    o.x = bf2f(pv[0]); o.y = bf2f(pv[1]); o.z = bf2f(pv[2]); o.w = bf2f(pv[3]);
    *(float4*)(slab + (size_t)c * 4) = o;
  }

  // ---- Phase 5: ctx = P @ V ----
  const unsigned short* vbase = Vt + (size_t)(h*DHH + w*16 + l16) * MT + b*SS + quad*8;
  f32x4 accp[2] = {};
  #pragma unroll 8
  for (int ks = 0; ks < 32; ks++) {
    bf16x8 bv = as_bf16x8(*(const u16x8*)(vbase + ks*32));
    bf16x8 a0 = as_bf16x8(*(const u16x8*)&Ps[l16][ks*32 + quad*8]);
    bf16x8 a1 = as_bf16x8(*(const u16x8*)&Ps[16 + l16][ks*32 + quad*8]);
    accp[0] = MFMA(a0, bv, accp[0]);
    accp[1] = MFMA(a1, bv, accp[1]);
  }
  #pragma unroll
  for (int i = 0; i < 2; i++)
    #pragma unroll
    for (int rr = 0; rr < 4; rr++)
      ctx[(size_t)(b*SS + q0 + i*16 + quad*4 + rr) * DD + h*DHH + w*16 + l16] =
          accp[i][rr];
}

extern "C" void kernel_launch(void* const* d_in, const int* in_sizes, int n_in,
                              void* d_out, int out_size, void* d_ws, size_t ws_size,
                              hipStream_t stream) {
  const float* query = (const float*)d_in[0];
  const float* key   = (const float*)d_in[1];
  const float* value = (const float*)d_in[2];
  const float* Wq    = (const float*)d_in[3];
  const float* bq    = (const float*)d_in[4];
  const float* Wk    = (const float*)d_in[5];
  const float* bk    = (const float*)d_in[6];
  const float* Wv    = (const float*)d_in[7];
  const float* bv    = (const float*)d_in[8];

  float* ctx  = (float*)d_out;
  float* attn = ctx + (size_t)BB * SS * DD;

  // Persistent bf16 Q/K/Vt in ws (24 MB, known-safe size)
  unsigned short* Qb = (unsigned short*)d_ws;
  unsigned short* Kb = Qb + (size_t)MT * DD;
  unsigned short* Vt = Kb + (size_t)MT * DD;

  // Transient staging (X3: 24 MB, Wt3: 6 MB) lives in the attn region of
  // d_out — dead by the time fused_attn overwrites it.
  unsigned short* X3  = (unsigned short*)attn;
  unsigned short* Wt3 = X3 + (size_t)3 * MT * DD;

  dim3 gc(MT * DD / (256 * 8), 3);                   // 2048 x 3
  conv_x3<<<gc, 256, 0, stream>>>(query, key, value, X3);

  dim3 gw(DD / 64, DD / 64, 3);                      // 16 x 16 x 3
  conv_wT3<<<gw, 256, 0, stream>>>(Wq, Wk, Wv, Wt3);

  dim3 gg(MT / 128, DD / 64, 3);                     // 32 x 16 x 3 = 1536 blocks
  gemm3<<<gg, 256, 0, stream>>>(X3, Wt3, bq, bk, bv, Qb, Kb, Vt);

  dim3 g2(SS / 32, BB * HH);                         // 32 x 64
  fused_attn<<<g2, 256, 0, stream>>>(Qb, Kb, Vt, attn, ctx);
}